// Round 8
// baseline (194.787 us; speedup 1.0000x reference)
//
#include <hip/hip_runtime.h>

// CNF: B=262144 samples, D=8, H=64.  outputs: dz_dt (B*8) | dlogp (B) | g (B), f32.
// f16 MFMA formulation: transposed GEMMs (features=M, samples=N=16 per wave).

#define BATCH 262144

typedef _Float16 h16;
typedef __attribute__((ext_vector_type(2))) __fp16 f16x2;   // cvt_pkrtz's return type
typedef __attribute__((ext_vector_type(8))) _Float16 half8;
typedef __attribute__((ext_vector_type(4))) float f32x4;

#define MFMA16(a, b, c) __builtin_amdgcn_mfma_f32_16x16x32_f16((a), (b), (c), 0, 0, 0)

// ws byte layout
#define WS_A   0        // 60 A-frag slots: [slot][lane 0..63][8 h16] = 60 KiB
#define WS_WO  61440    // woT_pk: [d 0..7][k 0..63] h16 = 1 KiB
#define WS_E   62464    // E_lay:  [d][g][mt*4+r] f32 = 2 KiB
#define WS_B   64512    // blay:   [6 layers][64] f32 (D-layout index g*16+mt*4+r)
#define WS_BO  66048    // bo_lay: [16] f32 (b1_o in D-layout rows, 0-padded)

__device__ __forceinline__ float tanh_fast(float x) {
    float e = __builtin_amdgcn_exp2f(x * 2.8853900817779268f); // 2*log2(e)
    return 1.0f - 2.0f * __builtin_amdgcn_rcpf(e + 1.0f);
}

// ---------------- prep: build weight fragments in ws ----------------
__global__ void __launch_bounds__(256) prep(
    const float* __restrict__ w1_0, const float* __restrict__ w1_1,
    const float* __restrict__ w1_2, const float* __restrict__ w1_o,
    const float* __restrict__ w2_0, const float* __restrict__ w2_1,
    const float* __restrict__ w2_2, const float* __restrict__ w2_o,
    const float* __restrict__ b1_0, const float* __restrict__ b1_1,
    const float* __restrict__ b1_2, const float* __restrict__ b1_o,
    const float* __restrict__ b2_0, const float* __restrict__ b2_1,
    const float* __restrict__ b2_2, char* __restrict__ ws)
{
    int t = blockIdx.x * 256 + threadIdx.x;
    if (t < 3840) {                     // A-frag tasks: (slot, lane)
        int slot = t >> 6, lane = t & 63;
        int mrow = lane & 15, kg = lane >> 4;
        half8 v;
        #pragma unroll
        for (int kk = 0; kk < 8; ++kk) {
            int mt = 0, ks = 0;
            float val = 0.0f;
            if (slot < 4) {                     // net1 W0^T, K=9 padded to 32
                mt = slot; int k = kg * 8 + kk; int m = mt * 16 + mrow;
                val = (k < 9) ? w1_0[k * 64 + m] : 0.0f;
            } else if (slot < 12) {             // net1 W1^T
                int s = slot - 4; mt = s >> 1; ks = s & 1;
                int k = ks * 32 + kg * 8 + kk; int m = mt * 16 + mrow;
                val = w1_1[k * 64 + m];
            } else if (slot < 20) {             // net1 W2^T
                int s = slot - 12; mt = s >> 1; ks = s & 1;
                int k = ks * 32 + kg * 8 + kk; int m = mt * 16 + mrow;
                val = w1_2[k * 64 + m];
            } else if (slot < 22) {             // Wo^T (8x64), rows >=8 zero
                ks = slot - 20; int k = ks * 32 + kg * 8 + kk;
                val = (mrow < 8) ? w1_o[k * 8 + mrow] : 0.0f;
            } else if (slot < 26) {             // net2 W0^T
                mt = slot - 22; int k = kg * 8 + kk; int m = mt * 16 + mrow;
                val = (k < 9) ? w2_0[k * 64 + m] : 0.0f;
            } else if (slot < 34) {             // net2 W1^T
                int s = slot - 26; mt = s >> 1; ks = s & 1;
                int k = ks * 32 + kg * 8 + kk; int m = mt * 16 + mrow;
                val = w2_1[k * 64 + m];
            } else if (slot < 42) {             // net2 W2^T
                int s = slot - 34; mt = s >> 1; ks = s & 1;
                int k = ks * 32 + kg * 8 + kk; int m = mt * 16 + mrow;
                val = w2_2[k * 64 + m];
            } else if (slot < 44) {             // w2_o^T (1x64), row 0 only
                ks = slot - 42; int k = ks * 32 + kg * 8 + kk;
                val = (mrow == 0) ? w2_o[k] : 0.0f;
            } else if (slot < 52) {             // w1_2 direct (trace G1)
                int s = slot - 44; mt = s >> 1; ks = s & 1;
                int k = ks * 32 + kg * 8 + kk; int m = mt * 16 + mrow;
                val = w1_2[m * 64 + k];
            } else {                            // w1_1 direct (trace G2)
                int s = slot - 52; mt = s >> 1; ks = s & 1;
                int k = ks * 32 + kg * 8 + kk; int m = mt * 16 + mrow;
                val = w1_1[m * 64 + k];
            }
            v[kk] = (h16)val;
        }
        *(half8*)((h16*)(ws + WS_A) + (size_t)slot * 512 + (size_t)lane * 8) = v;
    } else if (t < 4352) {              // woT_pk[d][k] = w1_o[k,d]
        int e = t - 3840; int d = e >> 6, k = e & 63;
        ((h16*)(ws + WS_WO))[e] = (h16)w1_o[k * 8 + d];
    } else if (t < 4864) {              // E_lay[d][g][mt*4+r] = w1_0[(d+1)*64 + 16mt+4g+r]
        int e = t - 4352; int d = e >> 6, g = (e >> 4) & 3, tr = e & 15;
        int mt = tr >> 2, r = tr & 3;
        int k = 16 * mt + 4 * g + r;
        ((float*)(ws + WS_E))[e] = w1_0[(d + 1) * 64 + k];
    } else if (t < 5248) {              // blay[layer][g*16+mt*4+r] = b[16mt+4g+r]
        int e = t - 4864; int layer = e >> 6, i = e & 63;
        int g = i >> 4, mt = (i >> 2) & 3, r = i & 3;
        int m = 16 * mt + 4 * g + r;
        const float* bsrc = (layer == 0) ? b1_0 : (layer == 1) ? b1_1 :
                            (layer == 2) ? b1_2 : (layer == 3) ? b2_0 :
                            (layer == 4) ? b2_1 : b2_2;
        ((float*)(ws + WS_B))[e] = bsrc[m];
    } else if (t < 5264) {              // bo_lay[g*4+r] = b1_o[4g+r] (0 for m>=8)
        int i = t - 5248; int g = i >> 2, r = i & 3;
        int m = 4 * g + r;
        ((float*)(ws + WS_BO))[i] = (m < 8) ? b1_o[m] : 0.0f;
    }
}

// ---------------- main kernel ----------------
__global__ void __launch_bounds__(256) cnf_mfma(
    const float* __restrict__ tp, const float* __restrict__ zp,
    const float* __restrict__ b2_o, const char* __restrict__ ws,
    float* __restrict__ out)
{
    // per-wave private LDS tile: [16 samples][64 feats] f16, XOR-swizzled
    __shared__ __align__(16) h16 xbuf[4][1024];

    const int lane = threadIdx.x & 63;
    const int wv = threadIdx.x >> 6;
    const int c = lane & 15;        // sample column within wave
    const int g = lane >> 4;        // lane k/m-group
    const int sIdx = blockIdx.x * 64 + wv * 16 + c;
    const int swz = (c & 7) << 3;   // element-index XOR swizzle
    h16* xb = xbuf[wv];

    int wadr[4];
    #pragma unroll
    for (int mt = 0; mt < 4; ++mt) wadr[mt] = (c * 64 + mt * 16 + 4 * g) ^ swz;
    const int radr0 = (c * 64 + 8 * g) ^ swz;
    const int radr1 = (c * 64 + 32 + 8 * g) ^ swz;

    const h16*   wsA  = (const h16*)(ws + WS_A);
    const h16*   wsWo = (const h16*)(ws + WS_WO);
    const float* wsE  = (const float*)(ws + WS_E);
    const float* wsB  = (const float*)(ws + WS_B);
    const float* wsBo = (const float*)(ws + WS_BO);

    const float tt = tp[0];
    const f32x4 zl = *(const f32x4*)(zp + (size_t)sIdx * 8);
    const f32x4 zh = *(const f32x4*)(zp + (size_t)sIdx * 8 + 4);

    // B-frag of input s^T = [t, z]^T (K=9 padded to 32): col=c, k=8g+kk
    half8 b0f;
    #pragma unroll
    for (int i = 0; i < 8; ++i) b0f[i] = (h16)0.0f;
    if (g == 0) {
        b0f[0] = (h16)tt;
        b0f[1] = (h16)zl[0]; b0f[2] = (h16)zl[1]; b0f[3] = (h16)zl[2];
        b0f[4] = (h16)zl[3]; b0f[5] = (h16)zh[0]; b0f[6] = (h16)zh[1];
        b0f[7] = (h16)zh[2];
    } else if (g == 1) {
        b0f[0] = (h16)zh[3];
    }

    f32x4 d[4], t1v[4];
    f16x2 t2h[8];

    // ===== net1 L0 =====
    #pragma unroll
    for (int mt = 0; mt < 4; ++mt) {
        f32x4 acc = *(const f32x4*)(wsB + 0 * 64 + g * 16 + mt * 4);
        d[mt] = MFMA16(*(const half8*)(wsA + (0 + mt) * 512 + lane * 8), b0f, acc);
    }
    #pragma unroll
    for (int mt = 0; mt < 4; ++mt) {
        float x0 = tanh_fast(d[mt][0]), x1 = tanh_fast(d[mt][1]);
        float x2 = tanh_fast(d[mt][2]), x3 = tanh_fast(d[mt][3]);
        t1v[mt][0] = fmaf(-x0, x0, 1.0f); t1v[mt][1] = fmaf(-x1, x1, 1.0f);
        t1v[mt][2] = fmaf(-x2, x2, 1.0f); t1v[mt][3] = fmaf(-x3, x3, 1.0f);
        union { f16x2 h[2]; uint2 u; } pk;
        pk.h[0] = __builtin_amdgcn_cvt_pkrtz(x0, x1);
        pk.h[1] = __builtin_amdgcn_cvt_pkrtz(x2, x3);
        *(uint2*)&xb[wadr[mt]] = pk.u;
    }

    // ===== net1 L1 =====
    {
        half8 bf0 = *(const half8*)&xb[radr0];
        half8 bf1 = *(const half8*)&xb[radr1];
        #pragma unroll
        for (int mt = 0; mt < 4; ++mt) {
            f32x4 acc = *(const f32x4*)(wsB + 1 * 64 + g * 16 + mt * 4);
            acc = MFMA16(*(const half8*)(wsA + (4 + mt * 2) * 512 + lane * 8), bf0, acc);
            acc = MFMA16(*(const half8*)(wsA + (5 + mt * 2) * 512 + lane * 8), bf1, acc);
            d[mt] = acc;
        }
    }
    #pragma unroll
    for (int mt = 0; mt < 4; ++mt) {
        float x0 = tanh_fast(d[mt][0]), x1 = tanh_fast(d[mt][1]);
        float x2 = tanh_fast(d[mt][2]), x3 = tanh_fast(d[mt][3]);
        t2h[2 * mt]     = __builtin_amdgcn_cvt_pkrtz(fmaf(-x0, x0, 1.0f), fmaf(-x1, x1, 1.0f));
        t2h[2 * mt + 1] = __builtin_amdgcn_cvt_pkrtz(fmaf(-x2, x2, 1.0f), fmaf(-x3, x3, 1.0f));
        union { f16x2 h[2]; uint2 u; } pk;
        pk.h[0] = __builtin_amdgcn_cvt_pkrtz(x0, x1);
        pk.h[1] = __builtin_amdgcn_cvt_pkrtz(x2, x3);
        *(uint2*)&xb[wadr[mt]] = pk.u;
    }

    // ===== net1 L2 =====
    {
        half8 bf0 = *(const half8*)&xb[radr0];
        half8 bf1 = *(const half8*)&xb[radr1];
        #pragma unroll
        for (int mt = 0; mt < 4; ++mt) {
            f32x4 acc = *(const f32x4*)(wsB + 2 * 64 + g * 16 + mt * 4);
            acc = MFMA16(*(const half8*)(wsA + (12 + mt * 2) * 512 + lane * 8), bf0, acc);
            acc = MFMA16(*(const half8*)(wsA + (13 + mt * 2) * 512 + lane * 8), bf1, acc);
            d[mt] = acc;
        }
    }
    #pragma unroll
    for (int mt = 0; mt < 4; ++mt) {
        float x0 = tanh_fast(d[mt][0]), x1 = tanh_fast(d[mt][1]);
        float x2 = tanh_fast(d[mt][2]), x3 = tanh_fast(d[mt][3]);
        union { f16x2 h[2]; uint2 u; } pk;
        pk.h[0] = __builtin_amdgcn_cvt_pkrtz(x0, x1);
        pk.h[1] = __builtin_amdgcn_cvt_pkrtz(x2, x3);
        *(uint2*)&xb[wadr[mt]] = pk.u;
    }

    // hoist trace G1 A-frags (w1_2 direct, slots 44..51) into registers
    half8 gA[8];
    #pragma unroll
    for (int s = 0; s < 8; ++s)
        gA[s] = *(const half8*)(wsA + (44 + s) * 512 + lane * 8);

    // x3 B-frags (used by dz AND t3)
    half8 xf0 = *(const half8*)&xb[radr0];
    half8 xf1 = *(const half8*)&xb[radr1];

    // ===== dz_dt = Wo^T x3^T + b1_o =====
    {
        f32x4 dz = *(const f32x4*)(wsBo + g * 4);
        dz = MFMA16(*(const half8*)(wsA + 20 * 512 + lane * 8), xf0, dz);
        dz = MFMA16(*(const half8*)(wsA + 21 * 512 + lane * 8), xf1, dz);
        if (g < 2)
            *(f32x4*)(out + (size_t)sIdx * 8 + g * 4) = dz;
    }

    // t3 B-frags directly in packed f16 (no LDS round-trip)
    half8 one8;
    #pragma unroll
    for (int i = 0; i < 8; ++i) one8[i] = (h16)1.0f;
    const half8 t3f0 = one8 - xf0 * xf0;
    const half8 t3f1 = one8 - xf1 * xf1;

    // ===== trace: 8 tangents; t1 deferred via tacc ====
    f32x4 tacc[4];
    #pragma unroll
    for (int mt = 0; mt < 4; ++mt) tacc[mt] = (f32x4){0.0f, 0.0f, 0.0f, 0.0f};

    #pragma unroll 1
    for (int d0 = 0; d0 < 8; ++d0) {
        half8 w0f = *(const half8*)(wsWo + d0 * 64 + 8 * g);
        half8 w1f = *(const half8*)(wsWo + d0 * 64 + 32 + 8 * g);
        half8 sA0 = t3f0 * w0f;
        half8 sA1 = t3f1 * w1f;
        // G1: rr = W2 sA^T
        f32x4 rr[4];
        #pragma unroll
        for (int mt = 0; mt < 4; ++mt) {
            f32x4 acc = {0.0f, 0.0f, 0.0f, 0.0f};
            acc = MFMA16(gA[2 * mt], sA0, acc);
            acc = MFMA16(gA[2 * mt + 1], sA1, acc);
            rr[mt] = acc;
        }
        // sB = t2 ∘ rr (packed f16) -> xb
        #pragma unroll
        for (int mt = 0; mt < 4; ++mt) {
            union { f16x2 h[2]; uint2 u; } pk;
            pk.h[0] = __builtin_amdgcn_cvt_pkrtz(rr[mt][0], rr[mt][1]) * t2h[2 * mt];
            pk.h[1] = __builtin_amdgcn_cvt_pkrtz(rr[mt][2], rr[mt][3]) * t2h[2 * mt + 1];
            *(uint2*)&xb[wadr[mt]] = pk.u;
        }
        half8 sb0 = *(const half8*)&xb[radr0];
        half8 sb1 = *(const half8*)&xb[radr1];
        // G2: q = W1 sB^T ; tacc += q ∘ E_d0
        #pragma unroll
        for (int mt = 0; mt < 4; ++mt) {
            f32x4 acc = {0.0f, 0.0f, 0.0f, 0.0f};
            acc = MFMA16(*(const half8*)(wsA + (52 + mt * 2) * 512 + lane * 8), sb0, acc);
            acc = MFMA16(*(const half8*)(wsA + (53 + mt * 2) * 512 + lane * 8), sb1, acc);
            f32x4 e = *(const f32x4*)(wsE + d0 * 64 + g * 16 + mt * 4);
            #pragma unroll
            for (int r = 0; r < 4; ++r) tacc[mt][r] = fmaf(acc[r], e[r], tacc[mt][r]);
        }
    }
    // apply t1 once, horizontal-reduce, cross-lane-group reduce
    float tr;
    {
        f32x4 tm = tacc[0] * t1v[0];
        #pragma unroll
        for (int mt = 1; mt < 4; ++mt) {
            #pragma unroll
            for (int r = 0; r < 4; ++r) tm[r] = fmaf(tacc[mt][r], t1v[mt][r], tm[r]);
        }
        tr = tm[0] + tm[1] + tm[2] + tm[3];
    }
    tr += __shfl_xor(tr, 16);
    tr += __shfl_xor(tr, 32);

    // ===== net2 (b0f still live; xb reused) =====
    #pragma unroll
    for (int mt = 0; mt < 4; ++mt) {
        f32x4 acc = *(const f32x4*)(wsB + 3 * 64 + g * 16 + mt * 4);
        d[mt] = MFMA16(*(const half8*)(wsA + (22 + mt) * 512 + lane * 8), b0f, acc);
    }
    #pragma unroll
    for (int mt = 0; mt < 4; ++mt) {
        union { f16x2 h[2]; uint2 u; } pk;
        pk.h[0] = __builtin_amdgcn_cvt_pkrtz(tanh_fast(d[mt][0]), tanh_fast(d[mt][1]));
        pk.h[1] = __builtin_amdgcn_cvt_pkrtz(tanh_fast(d[mt][2]), tanh_fast(d[mt][3]));
        *(uint2*)&xb[wadr[mt]] = pk.u;
    }
    #pragma unroll 1
    for (int L = 0; L < 2; ++L) {   // net2 L1, L2
        int sbase = (L == 0) ? 26 : 34;
        half8 bf0 = *(const half8*)&xb[radr0];
        half8 bf1 = *(const half8*)&xb[radr1];
        #pragma unroll
        for (int mt = 0; mt < 4; ++mt) {
            f32x4 acc = *(const f32x4*)(wsB + (4 + L) * 64 + g * 16 + mt * 4);
            acc = MFMA16(*(const half8*)(wsA + (sbase + mt * 2) * 512 + lane * 8), bf0, acc);
            acc = MFMA16(*(const half8*)(wsA + (sbase + mt * 2 + 1) * 512 + lane * 8), bf1, acc);
            d[mt] = acc;
        }
        #pragma unroll
        for (int mt = 0; mt < 4; ++mt) {
            union { f16x2 h[2]; uint2 u; } pk;
            pk.h[0] = __builtin_amdgcn_cvt_pkrtz(tanh_fast(d[mt][0]), tanh_fast(d[mt][1]));
            pk.h[1] = __builtin_amdgcn_cvt_pkrtz(tanh_fast(d[mt][2]), tanh_fast(d[mt][3]));
            *(uint2*)&xb[wadr[mt]] = pk.u;
        }
    }
    float gval;
    {
        half8 bf0 = *(const half8*)&xb[radr0];
        half8 bf1 = *(const half8*)&xb[radr1];
        f32x4 acc = {b2_o[0], 0.0f, 0.0f, 0.0f};
        acc = MFMA16(*(const half8*)(wsA + 42 * 512 + lane * 8), bf0, acc);
        acc = MFMA16(*(const half8*)(wsA + 43 * 512 + lane * 8), bf1, acc);
        gval = acc[0];   // valid at g==0 (row m=0)
    }

    if (g == 0) {
        out[(size_t)BATCH * 8 + sIdx] = gval - tr;  // dlogp_z_dt
        out[(size_t)BATCH * 9 + sIdx] = gval;       // g
    }
}

extern "C" void kernel_launch(void* const* d_in, const int* in_sizes, int n_in,
                              void* d_out, int out_size, void* d_ws, size_t ws_size,
                              hipStream_t stream) {
    const float* tp   = (const float*)d_in[0];
    const float* zp   = (const float*)d_in[1];
    // d_in[2] = logp_z (unused)
    const float* w1_0 = (const float*)d_in[3];
    const float* b1_0 = (const float*)d_in[4];
    const float* w1_1 = (const float*)d_in[5];
    const float* b1_1 = (const float*)d_in[6];
    const float* w1_2 = (const float*)d_in[7];
    const float* b1_2 = (const float*)d_in[8];
    const float* w1_o = (const float*)d_in[9];
    const float* b1_o = (const float*)d_in[10];
    const float* w2_0 = (const float*)d_in[11];
    const float* b2_0 = (const float*)d_in[12];
    const float* w2_1 = (const float*)d_in[13];
    const float* b2_1 = (const float*)d_in[14];
    const float* w2_2 = (const float*)d_in[15];
    const float* b2_2 = (const float*)d_in[16];
    const float* w2_o = (const float*)d_in[17];
    const float* b2_o = (const float*)d_in[18];

    char* ws = (char*)d_ws;
    float* out = (float*)d_out;

    hipLaunchKernelGGL(prep, dim3(21), dim3(256), 0, stream,
                       w1_0, w1_1, w1_2, w1_o, w2_0, w2_1, w2_2, w2_o,
                       b1_0, b1_1, b1_2, b1_o, b2_0, b2_1, b2_2, ws);
    hipLaunchKernelGGL(cnf_mfma, dim3(BATCH / 64), dim3(256), 0, stream,
                       tp, zp, b2_o, ws, out);
}